// Round 19
// baseline (233.865 us; speedup 1.0000x reference)
//
#include <hip/hip_runtime.h>
#include <hip/hip_bf16.h>

// GRU-D cell: B=16384, I=128, D=16 -- R19 = R16 + outer b-tile loop.
// Minimal delta from the best kernel (R16, 108 us): each block keeps its
// 16-i range and loops over 8 b-tiles (tile k = y + k*128: marching slab
// preserved). Isolates the ONE untested mechanism from R17/R18 without
// their failure modes (no register staging -> no spill; single 16.6-KB
// buffer -> 9-blocks/CU capacity, whole 1024-block grid co-resident):
//  (1) U/W/V/b gathers (57 KB/block, ~92 VMEM insts/tile) become L1-warm
//      after tile 0 (were cold-L2 for every one of 8192 blocks in R16).
//  (2) zero block turnover: no dispatch/tail overhead, blocks never drain.
// Phases per tile identical to R16: contiguous load+mult -> LDS; lane-local
// MFMA (3 mfma/iter, hh-side hi/lo compensation, gate-init as C-input);
// in-place out -> LDS; contiguous unstage.

typedef float  f32x4_t  __attribute__((ext_vector_type(4)));
typedef short  bf16x8_t __attribute__((ext_vector_type(8)));

constexpr int I_TOT = 128;
constexpr int ROWL  = 2048;   // floats per batch row (I*D)
constexpr int SW    = 260;    // LDS row stride in words (256 + 4 pad)
constexpr int NTK   = 8;      // b-tiles per block
constexpr int YB    = 128;    // grid.y

__device__ __forceinline__ unsigned short bf16c(float x) {
    union { __hip_bfloat16 b; unsigned short u; } cv;
    cv.b = __float2bfloat16(x);
    return cv.u;
}
__device__ __forceinline__ float bf16_to_f(unsigned short b) {
    union { float f; unsigned u; } c; c.u = ((unsigned)b) << 16;
    return c.f;
}
__device__ __forceinline__ float fast_sigmoid(float x) {
    float e = __expf(-x);
    return __builtin_amdgcn_rcpf(1.0f + e);
}
__device__ __forceinline__ float fast_tanh(float x) {
    x = fminf(fmaxf(x, -10.0f), 10.0f);
    float e = __expf(-2.0f * x);
    return (1.0f - e) * __builtin_amdgcn_rcpf(1.0f + e);
}

// compensated A fragment: [hi(a0..a3) | lo(a0..a3)]
__device__ __forceinline__ bf16x8_t build_a(float a0, float a1, float a2, float a3) {
    unsigned short h0 = bf16c(a0), h1 = bf16c(a1),
                   h2 = bf16c(a2), h3 = bf16c(a3);
    unsigned short l0 = bf16c(a0 - bf16_to_f(h0));
    unsigned short l1 = bf16c(a1 - bf16_to_f(h1));
    unsigned short l2 = bf16c(a2 - bf16_to_f(h2));
    unsigned short l3 = bf16c(a3 - bf16_to_f(h3));
    bf16x8_t A;
    A[0] = (short)h0; A[1] = (short)h1; A[2] = (short)h2; A[3] = (short)h3;
    A[4] = (short)l0; A[5] = (short)l1; A[6] = (short)l2; A[7] = (short)l3;
    return A;
}

// U fragment, hi only, duplicated across both K halves
__device__ __forceinline__ bf16x8_t build_u(float u0, float u1, float u2, float u3) {
    unsigned short h0 = bf16c(u0), h1 = bf16c(u1),
                   h2 = bf16c(u2), h3 = bf16c(u3);
    bf16x8_t B;
    B[0] = (short)h0; B[1] = (short)h1; B[2] = (short)h2; B[3] = (short)h3;
    B[4] = (short)h0; B[5] = (short)h1; B[6] = (short)h2; B[7] = (short)h3;
    return B;
}

__device__ __forceinline__ f32x4_t mm(bf16x8_t a, bf16x8_t b, f32x4_t c) {
    return __builtin_amdgcn_mfma_f32_16x16x32_bf16(a, b, c, 0, 0, 0);
}

__global__ __launch_bounds__(256)
__attribute__((amdgpu_waves_per_eu(4, 8)))
void gru_d_mfma(
    const float* __restrict__ h,
    const float* __restrict__ X,
    const float* __restrict__ M,
    const float* __restrict__ gam,
    const float* __restrict__ W_r, const float* __restrict__ W_z, const float* __restrict__ W_h,
    const float* __restrict__ U_r, const float* __restrict__ U_z, const float* __restrict__ U_h,
    const float* __restrict__ V_r, const float* __restrict__ V_z, const float* __restrict__ V_h,
    const float* __restrict__ b_r, const float* __restrict__ b_z, const float* __restrict__ b_h,
    float* __restrict__ out)
{
    __shared__ __align__(16) float shh[16 * SW];

    const int t  = threadIdx.x;
    const int w  = t >> 6;              // wave in block
    const int l  = t & 63;              // lane
    const int bi = l & 15;              // batch row within tile (phase 2)
    const int dA = (l >> 4) * 4;        // d-slot / out-col base (phase 2)
    const int r0 = 4 * w;               // staging rows for this wave

    const int i0  = blockIdx.x * 16;    // block's feature range (fixed)
    const int iw0 = i0 + w * 4;         // this wave's first i

    #pragma unroll 1
    for (int k = 0; k < NTK; ++k) {
        const int b0 = (blockIdx.y + k * YB) * 16;

        if (k > 0) __syncthreads();      // phase 3 of k-1 done reading shh

        // ======== Phase 1: contiguous stream -> hh in LDS ========
        {
#define STAGE(rr)                                                             \
            {                                                                 \
                const size_t gb = (size_t)(b0 + r0 + (rr)) * ROWL + i0 * 16;  \
                float4 hv = *reinterpret_cast<const float4*>(h   + gb + 4*l); \
                float4 gv = *reinterpret_cast<const float4*>(gam + gb + 4*l); \
                float4 p;                                                     \
                p.x = hv.x * gv.x; p.y = hv.y * gv.y;                         \
                p.z = hv.z * gv.z; p.w = hv.w * gv.w;                         \
                *reinterpret_cast<float4*>(&shh[(r0 + (rr)) * SW + 4*l]) = p; \
            }
            STAGE(0) STAGE(1) STAGE(2) STAGE(3)
#undef STAGE
        }
        __syncthreads();

        // ======== Phase 2: lane-local MFMA over 4 i's; out -> LDS ========
        const size_t xrow = (size_t)(b0 + bi) * I_TOT;

        float4 phh = *reinterpret_cast<const float4*>(&shh[bi * SW + (w * 4) * 16 + dA]);
        float px = X[xrow + iw0];
        float pm = M[xrow + iw0];
        const float* Urp = U_r + iw0 * 256 + bi;
        const float* Uzp = U_z + iw0 * 256 + bi;
        const float* Uhp = U_h + iw0 * 256 + bi;
        float pur0 = Urp[(dA+0)*16], pur1 = Urp[(dA+1)*16],
              pur2 = Urp[(dA+2)*16], pur3 = Urp[(dA+3)*16];
        float puz0 = Uzp[(dA+0)*16], puz1 = Uzp[(dA+1)*16],
              puz2 = Uzp[(dA+2)*16], puz3 = Uzp[(dA+3)*16];
        float puh0 = Uhp[(dA+0)*16], puh1 = Uhp[(dA+1)*16],
              puh2 = Uhp[(dA+2)*16], puh3 = Uhp[(dA+3)*16];

        #pragma unroll
        for (int it = 0; it < 4; ++it) {
            const int i = iw0 + it;

            const float4 wr4 = *reinterpret_cast<const float4*>(W_r + i*16 + dA);
            const float4 wz4 = *reinterpret_cast<const float4*>(W_z + i*16 + dA);
            const float4 wh4 = *reinterpret_cast<const float4*>(W_h + i*16 + dA);
            const float4 vr4 = *reinterpret_cast<const float4*>(V_r + i*16 + dA);
            const float4 vz4 = *reinterpret_cast<const float4*>(V_z + i*16 + dA);
            const float4 vh4 = *reinterpret_cast<const float4*>(V_h + i*16 + dA);
            const float4 br4 = *reinterpret_cast<const float4*>(b_r + i*16 + dA);
            const float4 bz4 = *reinterpret_cast<const float4*>(b_z + i*16 + dA);
            const float4 bh4 = *reinterpret_cast<const float4*>(b_h + i*16 + dA);

            bf16x8_t BUr = build_u(pur0, pur1, pur2, pur3);
            bf16x8_t BUz = build_u(puz0, puz1, puz2, puz3);
            bf16x8_t BUh = build_u(puh0, puh1, puh2, puh3);

            float hh0 = phh.x, hh1 = phh.y, hh2 = phh.z, hh3 = phh.w;
            bf16x8_t Ahh = build_a(hh0, hh1, hh2, hh3);

            float4 nhh; float nx, nm;
            float nur0, nur1, nur2, nur3, nuz0, nuz1, nuz2, nuz3,
                  nuh0, nuh1, nuh2, nuh3;
            if (it < 3) {
                const int ipf = i + 1;
                nhh = *reinterpret_cast<const float4*>(
                    &shh[bi * SW + (w * 4 + it + 1) * 16 + dA]);
                nx = X[xrow + ipf];
                nm = M[xrow + ipf];
                const float* nUr = U_r + ipf * 256 + bi;
                const float* nUz = U_z + ipf * 256 + bi;
                const float* nUh = U_h + ipf * 256 + bi;
                nur0 = nUr[(dA+0)*16]; nur1 = nUr[(dA+1)*16];
                nur2 = nUr[(dA+2)*16]; nur3 = nUr[(dA+3)*16];
                nuz0 = nUz[(dA+0)*16]; nuz1 = nUz[(dA+1)*16];
                nuz2 = nUz[(dA+2)*16]; nuz3 = nUz[(dA+3)*16];
                nuh0 = nUh[(dA+0)*16]; nuh1 = nUh[(dA+1)*16];
                nuh2 = nUh[(dA+2)*16]; nuh3 = nUh[(dA+3)*16];
            }

            f32x4_t initR, initZ, initH;
            initR[0] = fmaf(px, wr4.x, fmaf(pm, vr4.x, br4.x));
            initR[1] = fmaf(px, wr4.y, fmaf(pm, vr4.y, br4.y));
            initR[2] = fmaf(px, wr4.z, fmaf(pm, vr4.z, br4.z));
            initR[3] = fmaf(px, wr4.w, fmaf(pm, vr4.w, br4.w));
            initZ[0] = fmaf(px, wz4.x, fmaf(pm, vz4.x, bz4.x));
            initZ[1] = fmaf(px, wz4.y, fmaf(pm, vz4.y, bz4.y));
            initZ[2] = fmaf(px, wz4.z, fmaf(pm, vz4.z, bz4.z));
            initZ[3] = fmaf(px, wz4.w, fmaf(pm, vz4.w, bz4.w));
            f32x4_t accR = mm(BUr, Ahh, initR);
            f32x4_t accZ = mm(BUz, Ahh, initZ);

            float rh0 = fast_sigmoid(accR[0]) * hh0;
            float rh1 = fast_sigmoid(accR[1]) * hh1;
            float rh2 = fast_sigmoid(accR[2]) * hh2;
            float rh3 = fast_sigmoid(accR[3]) * hh3;
            bf16x8_t Arh = build_a(rh0, rh1, rh2, rh3);

            initH[0] = fmaf(px, wh4.x, fmaf(pm, vh4.x, bh4.x));
            initH[1] = fmaf(px, wh4.y, fmaf(pm, vh4.y, bh4.y));
            initH[2] = fmaf(px, wh4.z, fmaf(pm, vh4.z, bh4.z));
            initH[3] = fmaf(px, wh4.w, fmaf(pm, vh4.w, bh4.w));
            f32x4_t accH = mm(BUh, Arh, initH);

            float4 o;
            {
                float z0 = fast_sigmoid(accZ[0]); float t0 = fast_tanh(accH[0]);
                o.x = fmaf(z0, hh0 - t0, t0);
                float z1 = fast_sigmoid(accZ[1]); float t1 = fast_tanh(accH[1]);
                o.y = fmaf(z1, hh1 - t1, t1);
                float z2 = fast_sigmoid(accZ[2]); float t2 = fast_tanh(accH[2]);
                o.z = fmaf(z2, hh2 - t2, t2);
                float z3 = fast_sigmoid(accZ[3]); float t3 = fast_tanh(accH[3]);
                o.w = fmaf(z3, hh3 - t3, t3);
            }
            // in-place: this lane's slot was read (prefetch) before write
            *reinterpret_cast<float4*>(&shh[bi * SW + (w * 4 + it) * 16 + dA]) = o;

            if (it < 3) {
                phh = nhh; px = nx; pm = nm;
                pur0 = nur0; pur1 = nur1; pur2 = nur2; pur3 = nur3;
                puz0 = nuz0; puz1 = nuz1; puz2 = nuz2; puz3 = nuz3;
                puh0 = nuh0; puh1 = nuh1; puh2 = nuh2; puh3 = nuh3;
            }
        }
        __syncthreads();

        // ======== Phase 3: contiguous unstage shh -> out ========
        {
#define UNSTAGE(rr)                                                           \
            {                                                                 \
                const size_t gb = (size_t)(b0 + r0 + (rr)) * ROWL + i0 * 16;  \
                float4 v = *reinterpret_cast<const float4*>(                  \
                    &shh[(r0 + (rr)) * SW + 4 * l]);                          \
                *reinterpret_cast<float4*>(out + gb + 4 * l) = v;             \
            }
            UNSTAGE(0) UNSTAGE(1) UNSTAGE(2) UNSTAGE(3)
#undef UNSTAGE
        }
    }
}

extern "C" void kernel_launch(void* const* d_in, const int* in_sizes, int n_in,
                              void* d_out, int out_size, void* d_ws, size_t ws_size,
                              hipStream_t stream) {
    const float* h       = (const float*)d_in[0];
    const float* X       = (const float*)d_in[1];
    const float* M       = (const float*)d_in[2];
    const float* gamma_h = (const float*)d_in[3];
    const float* W_r     = (const float*)d_in[4];
    const float* W_z     = (const float*)d_in[5];
    const float* W_h     = (const float*)d_in[6];
    const float* U_r     = (const float*)d_in[7];
    const float* U_z     = (const float*)d_in[8];
    const float* U_h     = (const float*)d_in[9];
    const float* V_r     = (const float*)d_in[10];
    const float* V_z     = (const float*)d_in[11];
    const float* V_h     = (const float*)d_in[12];
    const float* b_r     = (const float*)d_in[13];
    const float* b_z     = (const float*)d_in[14];
    const float* b_h     = (const float*)d_in[15];
    float* out = (float*)d_out;

    dim3 grid(I_TOT / 16, YB);   // (8, 128) = 1024 blocks, all co-resident
    dim3 block(256);
    gru_d_mfma<<<grid, block, 0, stream>>>(h, X, M, gamma_h,
                                           W_r, W_z, W_h,
                                           U_r, U_z, U_h,
                                           V_r, V_z, V_h,
                                           b_r, b_z, b_h,
                                           out);
}

// Round 20
// 106.107 us; speedup vs baseline: 2.2040x; 2.2040x over previous
//
#include <hip/hip_runtime.h>
#include <hip/hip_bf16.h>

// GRU-D cell: B=16384, I=128, D=16 -- fully-staged streams + lane-local MFMA.
// FINAL (revert to R16, the measured optimum at 108 us).
// R17 (register double-buffer): spilled -> 314 us. R18 (DMA double-buffer):
// occupancy collapse to 11% -> 119 us. R19 (outer b-loop param warmth):
// device-wide footprint fragmentation, FETCH 148->634 MB -> 234 us.
// R16's structure: per block (16 b-rows x 16 i's),
//   Phase 1: contiguous 1-KB wave loads of h/gamma -> hh staged in LDS
//   Phase 2: lane-local operand-swapped MFMA gates (3 mfma/iter, hh-side
//            hi/lo bf16 compensation, gate-init as MFMA C-input)
//   Phase 3: contiguous 1-KB wave stores LDS -> out
// All bulk HBM traffic is memcpy-shaped; WRITE_SIZE is exactly the 131072-KB
// ideal; ~287 MB total at ~2.3 TB/s effective. 17 structural variants
// (R3..R19) could not push this op's 64-B-granule gather/scatter past
// ~2.3 TB/s -- pattern roofline.

typedef float  f32x4_t  __attribute__((ext_vector_type(4)));
typedef short  bf16x8_t __attribute__((ext_vector_type(8)));

constexpr int I_TOT = 128;
constexpr int ROWL  = 2048;   // floats per batch row (I*D)
constexpr int SW    = 260;    // LDS row stride in words (256 + 4 pad)

__device__ __forceinline__ unsigned short bf16c(float x) {
    union { __hip_bfloat16 b; unsigned short u; } cv;
    cv.b = __float2bfloat16(x);
    return cv.u;
}
__device__ __forceinline__ float bf16_to_f(unsigned short b) {
    union { float f; unsigned u; } c; c.u = ((unsigned)b) << 16;
    return c.f;
}
__device__ __forceinline__ float fast_sigmoid(float x) {
    float e = __expf(-x);
    return __builtin_amdgcn_rcpf(1.0f + e);
}
__device__ __forceinline__ float fast_tanh(float x) {
    x = fminf(fmaxf(x, -10.0f), 10.0f);
    float e = __expf(-2.0f * x);
    return (1.0f - e) * __builtin_amdgcn_rcpf(1.0f + e);
}

// compensated A fragment: [hi(a0..a3) | lo(a0..a3)]
__device__ __forceinline__ bf16x8_t build_a(float a0, float a1, float a2, float a3) {
    unsigned short h0 = bf16c(a0), h1 = bf16c(a1),
                   h2 = bf16c(a2), h3 = bf16c(a3);
    unsigned short l0 = bf16c(a0 - bf16_to_f(h0));
    unsigned short l1 = bf16c(a1 - bf16_to_f(h1));
    unsigned short l2 = bf16c(a2 - bf16_to_f(h2));
    unsigned short l3 = bf16c(a3 - bf16_to_f(h3));
    bf16x8_t A;
    A[0] = (short)h0; A[1] = (short)h1; A[2] = (short)h2; A[3] = (short)h3;
    A[4] = (short)l0; A[5] = (short)l1; A[6] = (short)l2; A[7] = (short)l3;
    return A;
}

// U fragment, hi only, duplicated across both K halves
__device__ __forceinline__ bf16x8_t build_u(float u0, float u1, float u2, float u3) {
    unsigned short h0 = bf16c(u0), h1 = bf16c(u1),
                   h2 = bf16c(u2), h3 = bf16c(u3);
    bf16x8_t B;
    B[0] = (short)h0; B[1] = (short)h1; B[2] = (short)h2; B[3] = (short)h3;
    B[4] = (short)h0; B[5] = (short)h1; B[6] = (short)h2; B[7] = (short)h3;
    return B;
}

__device__ __forceinline__ f32x4_t mm(bf16x8_t a, bf16x8_t b, f32x4_t c) {
    return __builtin_amdgcn_mfma_f32_16x16x32_bf16(a, b, c, 0, 0, 0);
}

__global__ __launch_bounds__(256)
__attribute__((amdgpu_waves_per_eu(4, 8)))
void gru_d_mfma(
    const float* __restrict__ h,
    const float* __restrict__ X,
    const float* __restrict__ M,
    const float* __restrict__ gam,
    const float* __restrict__ W_r, const float* __restrict__ W_z, const float* __restrict__ W_h,
    const float* __restrict__ U_r, const float* __restrict__ U_z, const float* __restrict__ U_h,
    const float* __restrict__ V_r, const float* __restrict__ V_z, const float* __restrict__ V_h,
    const float* __restrict__ b_r, const float* __restrict__ b_z, const float* __restrict__ b_h,
    float* __restrict__ out)
{
    __shared__ __align__(16) float shh[16 * SW];

    const int t  = threadIdx.x;
    const int w  = t >> 6;              // wave in block
    const int l  = t & 63;              // lane
    const int bi = l & 15;              // batch row within tile (phase 2)
    const int dA = (l >> 4) * 4;        // d-slot / out-col base (phase 2)

    const int b0 = blockIdx.y * 16;     // b-tile
    const int i0 = blockIdx.x * 16;     // block's first feature (16-i tile)

    // ======== Phase 1: contiguous stream -> hh in LDS ========
    {
        const int r0 = 4 * w;
#define STAGE(rr)                                                             \
        {                                                                     \
            const size_t gb = (size_t)(b0 + r0 + (rr)) * ROWL + i0 * 16;      \
            float4 hv = *reinterpret_cast<const float4*>(h   + gb + 4 * l);   \
            float4 gv = *reinterpret_cast<const float4*>(gam + gb + 4 * l);   \
            float4 p;                                                         \
            p.x = hv.x * gv.x; p.y = hv.y * gv.y;                             \
            p.z = hv.z * gv.z; p.w = hv.w * gv.w;                             \
            *reinterpret_cast<float4*>(&shh[(r0 + (rr)) * SW + 4 * l]) = p;   \
        }
        STAGE(0) STAGE(1) STAGE(2) STAGE(3)
#undef STAGE
    }
    __syncthreads();

    // ======== Phase 2: lane-local MFMA over 4 i's; out -> LDS in place ====
    const int iw0 = i0 + w * 4;                         // this wave's first i
    const size_t xrow = (size_t)(b0 + bi) * I_TOT;      // X/M lane base

    // prefetch iteration 0
    float4 phh = *reinterpret_cast<const float4*>(&shh[bi * SW + (w * 4) * 16 + dA]);
    float px = X[xrow + iw0];
    float pm = M[xrow + iw0];
    const float* Urp = U_r + iw0 * 256 + bi;
    const float* Uzp = U_z + iw0 * 256 + bi;
    const float* Uhp = U_h + iw0 * 256 + bi;
    float pur0 = Urp[(dA+0)*16], pur1 = Urp[(dA+1)*16],
          pur2 = Urp[(dA+2)*16], pur3 = Urp[(dA+3)*16];
    float puz0 = Uzp[(dA+0)*16], puz1 = Uzp[(dA+1)*16],
          puz2 = Uzp[(dA+2)*16], puz3 = Uzp[(dA+3)*16];
    float puh0 = Uhp[(dA+0)*16], puh1 = Uhp[(dA+1)*16],
          puh2 = Uhp[(dA+2)*16], puh3 = Uhp[(dA+3)*16];

    #pragma unroll
    for (int it = 0; it < 4; ++it) {
        const int i = iw0 + it;

        // ---- W/V/b for current i (feed the MFMA C-input) ----
        const float4 wr4 = *reinterpret_cast<const float4*>(W_r + i*16 + dA);
        const float4 wz4 = *reinterpret_cast<const float4*>(W_z + i*16 + dA);
        const float4 wh4 = *reinterpret_cast<const float4*>(W_h + i*16 + dA);
        const float4 vr4 = *reinterpret_cast<const float4*>(V_r + i*16 + dA);
        const float4 vz4 = *reinterpret_cast<const float4*>(V_z + i*16 + dA);
        const float4 vh4 = *reinterpret_cast<const float4*>(V_h + i*16 + dA);
        const float4 br4 = *reinterpret_cast<const float4*>(b_r + i*16 + dA);
        const float4 bz4 = *reinterpret_cast<const float4*>(b_z + i*16 + dA);
        const float4 bh4 = *reinterpret_cast<const float4*>(b_h + i*16 + dA);

        // ---- U fragments (hi-only, duplicated) ----
        bf16x8_t BUr = build_u(pur0, pur1, pur2, pur3);
        bf16x8_t BUz = build_u(puz0, puz1, puz2, puz3);
        bf16x8_t BUh = build_u(puh0, puh1, puh2, puh3);

        // ---- hh (staged h*gamma): lane owns hh[bi][dA..dA+3] ----
        float hh0 = phh.x, hh1 = phh.y, hh2 = phh.z, hh3 = phh.w;
        bf16x8_t Ahh = build_a(hh0, hh1, hh2, hh3);

        // ---- prefetch next iteration (static guard, loop fully unrolled) ----
        float4 nhh; float nx, nm;
        float nur0, nur1, nur2, nur3, nuz0, nuz1, nuz2, nuz3, nuh0, nuh1, nuh2, nuh3;
        if (it < 3) {
            const int ipf = i + 1;
            nhh = *reinterpret_cast<const float4*>(
                &shh[bi * SW + (w * 4 + it + 1) * 16 + dA]);
            nx = X[xrow + ipf];
            nm = M[xrow + ipf];
            const float* nUr = U_r + ipf * 256 + bi;
            const float* nUz = U_z + ipf * 256 + bi;
            const float* nUh = U_h + ipf * 256 + bi;
            nur0 = nUr[(dA+0)*16]; nur1 = nUr[(dA+1)*16];
            nur2 = nUr[(dA+2)*16]; nur3 = nUr[(dA+3)*16];
            nuz0 = nUz[(dA+0)*16]; nuz1 = nUz[(dA+1)*16];
            nuz2 = nUz[(dA+2)*16]; nuz3 = nUz[(dA+3)*16];
            nuh0 = nUh[(dA+0)*16]; nuh1 = nUh[(dA+1)*16];
            nuh2 = nUh[(dA+2)*16]; nuh3 = nUh[(dA+3)*16];
        }

        // ---- r and z gates: one MFMA each, C = x*W + m*V + b ----
        f32x4_t initR, initZ, initH;
        initR[0] = fmaf(px, wr4.x, fmaf(pm, vr4.x, br4.x));
        initR[1] = fmaf(px, wr4.y, fmaf(pm, vr4.y, br4.y));
        initR[2] = fmaf(px, wr4.z, fmaf(pm, vr4.z, br4.z));
        initR[3] = fmaf(px, wr4.w, fmaf(pm, vr4.w, br4.w));
        initZ[0] = fmaf(px, wz4.x, fmaf(pm, vz4.x, bz4.x));
        initZ[1] = fmaf(px, wz4.y, fmaf(pm, vz4.y, bz4.y));
        initZ[2] = fmaf(px, wz4.z, fmaf(pm, vz4.z, bz4.z));
        initZ[3] = fmaf(px, wz4.w, fmaf(pm, vz4.w, bz4.w));
        f32x4_t accR = mm(BUr, Ahh, initR);
        f32x4_t accZ = mm(BUz, Ahh, initZ);

        // ---- rhh lane-local ----
        float rh0 = fast_sigmoid(accR[0]) * hh0;
        float rh1 = fast_sigmoid(accR[1]) * hh1;
        float rh2 = fast_sigmoid(accR[2]) * hh2;
        float rh3 = fast_sigmoid(accR[3]) * hh3;
        bf16x8_t Arh = build_a(rh0, rh1, rh2, rh3);

        // ---- h~ gate ----
        initH[0] = fmaf(px, wh4.x, fmaf(pm, vh4.x, bh4.x));
        initH[1] = fmaf(px, wh4.y, fmaf(pm, vh4.y, bh4.y));
        initH[2] = fmaf(px, wh4.z, fmaf(pm, vh4.z, bh4.z));
        initH[3] = fmaf(px, wh4.w, fmaf(pm, vh4.w, bh4.w));
        f32x4_t accH = mm(BUh, Arh, initH);

        // ---- out = z*hh + (1-z)*tanh(.), written IN PLACE to LDS ----
        float4 o;
        {
            float z0 = fast_sigmoid(accZ[0]); float t0 = fast_tanh(accH[0]);
            o.x = fmaf(z0, hh0 - t0, t0);
            float z1 = fast_sigmoid(accZ[1]); float t1 = fast_tanh(accH[1]);
            o.y = fmaf(z1, hh1 - t1, t1);
            float z2 = fast_sigmoid(accZ[2]); float t2 = fast_tanh(accH[2]);
            o.z = fmaf(z2, hh2 - t2, t2);
            float z3 = fast_sigmoid(accZ[3]); float t3 = fast_tanh(accH[3]);
            o.w = fmaf(z3, hh3 - t3, t3);
        }
        *reinterpret_cast<float4*>(&shh[bi * SW + (w * 4 + it) * 16 + dA]) = o;

        // ---- rotate prefetch ----
        if (it < 3) {
            phh = nhh; px = nx; pm = nm;
            pur0 = nur0; pur1 = nur1; pur2 = nur2; pur3 = nur3;
            puz0 = nuz0; puz1 = nuz1; puz2 = nuz2; puz3 = nuz3;
            puh0 = nuh0; puh1 = nuh1; puh2 = nuh2; puh3 = nuh3;
        }
    }
    __syncthreads();

    // ======== Phase 3: contiguous stream LDS -> out (mirror of phase 1) ====
    {
        const int r0 = 4 * w;
#define UNSTAGE(rr)                                                           \
        {                                                                     \
            const size_t gb = (size_t)(b0 + r0 + (rr)) * ROWL + i0 * 16;      \
            float4 v = *reinterpret_cast<const float4*>(                      \
                &shh[(r0 + (rr)) * SW + 4 * l]);                              \
            *reinterpret_cast<float4*>(out + gb + 4 * l) = v;                 \
        }
        UNSTAGE(0) UNSTAGE(1) UNSTAGE(2) UNSTAGE(3)
#undef UNSTAGE
    }
}

extern "C" void kernel_launch(void* const* d_in, const int* in_sizes, int n_in,
                              void* d_out, int out_size, void* d_ws, size_t ws_size,
                              hipStream_t stream) {
    const float* h       = (const float*)d_in[0];
    const float* X       = (const float*)d_in[1];
    const float* M       = (const float*)d_in[2];
    const float* gamma_h = (const float*)d_in[3];
    const float* W_r     = (const float*)d_in[4];
    const float* W_z     = (const float*)d_in[5];
    const float* W_h     = (const float*)d_in[6];
    const float* U_r     = (const float*)d_in[7];
    const float* U_z     = (const float*)d_in[8];
    const float* U_h     = (const float*)d_in[9];
    const float* V_r     = (const float*)d_in[10];
    const float* V_z     = (const float*)d_in[11];
    const float* V_h     = (const float*)d_in[12];
    const float* b_r     = (const float*)d_in[13];
    const float* b_z     = (const float*)d_in[14];
    const float* b_h     = (const float*)d_in[15];
    float* out = (float*)d_out;

    dim3 grid(I_TOT / 16, 16384 / 16);   // (8, 1024) = 8192 blocks
    dim3 block(256);
    gru_d_mfma<<<grid, block, 0, stream>>>(h, X, M, gamma_h,
                                           W_r, W_z, W_h,
                                           U_r, U_z, U_h,
                                           V_r, V_z, V_h,
                                           b_r, b_z, b_h,
                                           out);
}